// Round 10
// baseline (187.357 us; speedup 1.0000x reference)
//
#include <hip/hip_runtime.h>
#include <hip/hip_bf16.h>
#include <hip/hip_cooperative_groups.h>

namespace cg = cooperative_groups;

#define B_N 16384
#define TAU 0.25f
#define GS 68     // G leading dim (floats); 16B-aligned rows
#define YS 133    // Y leading dim (floats); ODD -> scalar access conflict-free

typedef float f32x4 __attribute__((ext_vector_type(4)));
typedef short s16x8 __attribute__((ext_vector_type(8)));

__device__ __forceinline__ void gl_lds16(const void* g, void* l) {
    __builtin_amdgcn_global_load_lds(
        (const __attribute__((address_space(1))) void*)g,
        (__attribute__((address_space(3))) void*)l, 16, 0, 0);
}

__device__ __forceinline__ unsigned short bf16_bits(float v) {
    __hip_bfloat16 h = __float2bfloat16(v);
    return *reinterpret_cast<unsigned short*>(&h);
}

__device__ __forceinline__ float readlane_f(float v, int l) {
    return __int_as_float(__builtin_amdgcn_readlane(__float_as_int(v), l));
}

// ---------------------------------------------------------------------------
// R19: ONE cooperative kernel. 256 blocks x 512 threads, 1 block/CU.
// Stage 1: blocks 0..63 = R17 prep (work guarded t<256; barriers
//          unconditional); blocks 64..191 = convert (512-thr mapping).
// grid.sync()  (device-scope visibility for Bht/Qg/xh/nrm)
// Stage 2: ALL blocks = R18 gemm+argmax+rescore body (m0 = b*64).
// LDS overlaid: prep {Y,G,Lti} (52.5 KB)  U  gemm {ldsA,scL,mrg} (38.4 KB).
// ---------------------------------------------------------------------------
__global__ __launch_bounds__(512) void fused_kfactor(const float* __restrict__ x,
                                                     const float* __restrict__ D,
                                                     unsigned short* __restrict__ xh,
                                                     float* __restrict__ nrm,
                                                     float* __restrict__ Qg,
                                                     unsigned short* __restrict__ Bht,
                                                     float* __restrict__ out) {
    __shared__ __align__(16) unsigned char smem[53760];
    __shared__ int sflags[64];
    __shared__ int scnt;
    __shared__ float ssum;
    __shared__ float scorr[8];

    const int t = threadIdx.x;
    const int b = blockIdx.x;

    // ======================= stage 1 =======================
    if (b < 64) {
        // ---------------- prep path (R17 internals) ----------------
        float* Y   = (float*)smem;                 // 64*133*4  = 34048 B
        float* G   = (float*)(smem + 34048);       // (64*68+64)*4 = 17664 B
        float* Lti = (float*)(smem + 51712);       // 512*4 = 2048 B -> 53760
        const int n = b;
        const float* Dn = D + (size_t)n * 8192;

        if (t < 256) {
            // Phase A: Y[j][c] = Dn[c][j]
            for (int e4 = t; e4 < 2048; e4 += 256) {
                const int c = e4 >> 4, j4 = (e4 & 15) * 4;
                const f32x4 v = ((const f32x4*)Dn)[e4];
                Y[(j4 + 0) * YS + c] = v.x;
                Y[(j4 + 1) * YS + c] = v.y;
                Y[(j4 + 2) * YS + c] = v.z;
                Y[(j4 + 3) * YS + c] = v.w;
            }
            // Phase B: gram from global (L1-hot)
            const int a0 = (t & 15) * 4, b0 = (t >> 4) * 4;
            float acc[4][4] = {};
            #pragma unroll 4
            for (int i = 0; i < 128; ++i) {
                const f32x4 av = *(const f32x4*)(Dn + i * 64 + a0);
                const f32x4 bv = *(const f32x4*)(Dn + i * 64 + b0);
                const float aa[4] = {av.x, av.y, av.z, av.w};
                const float bb[4] = {bv.x, bv.y, bv.z, bv.w};
                #pragma unroll
                for (int p = 0; p < 4; ++p)
                    #pragma unroll
                    for (int q = 0; q < 4; ++q) acc[p][q] = fmaf(aa[p], bb[q], acc[p][q]);
            }
            #pragma unroll
            for (int p = 0; p < 4; ++p)
                #pragma unroll
                for (int q = 0; q < 4; ++q) G[(a0 + p) * GS + b0 + q] = acc[p][q];
        }
        __syncthreads();

        // Phase C: blocked Cholesky (readlane diag chain)
        #pragma unroll
        for (int p8 = 0; p8 < 8; ++p8) {
            const int pb = p8 * 8;
            if (t < 64) {
                const int lane = t;
                const f32x4 v0 = *(const f32x4*)&G[lane * GS + pb];
                const f32x4 v1 = *(const f32x4*)&G[lane * GS + pb + 4];
                float g[8] = {v0.x, v0.y, v0.z, v0.w, v1.x, v1.y, v1.z, v1.w};
                #pragma unroll
                for (int kk = 0; kk < 8; ++kk) {
                    const int k = pb + kk;
                    const float dk = readlane_f(g[kk], k);
                    const float rinv = 1.0f / sqrtf(dk);
                    const float lik = g[kk] * rinv;
                    g[kk] = lik;
                    if (lane == 0) G[64 * GS + k] = rinv;
                    #pragma unroll
                    for (int jj = kk + 1; jj < 8; ++jj) {
                        const float ljk = readlane_f(lik, pb + jj);
                        g[jj] -= lik * ljk;
                    }
                }
                *(f32x4*)&G[lane * GS + pb]     = (f32x4){g[0], g[1], g[2], g[3]};
                *(f32x4*)&G[lane * GS + pb + 4] = (f32x4){g[4], g[5], g[6], g[7]};
            }
            __syncthreads();
            const int base = pb + 8;
            if (base < 64 && t < 256) {
                for (int i = base + (t >> 5); i < 64; i += 8) {
                    const f32x4 Li0 = *(const f32x4*)&G[i * GS + pb];
                    const f32x4 Li1 = *(const f32x4*)&G[i * GS + pb + 4];
                    for (int j = base + (t & 31); j < 64; j += 32) {
                        const f32x4 Lj0 = *(const f32x4*)&G[j * GS + pb];
                        const f32x4 Lj1 = *(const f32x4*)&G[j * GS + pb + 4];
                        float s = G[i * GS + j];
                        s -= Li0.x * Lj0.x + Li0.y * Lj0.y + Li0.z * Lj0.z + Li0.w * Lj0.w;
                        s -= Li1.x * Lj1.x + Li1.y * Lj1.y + Li1.z * Lj1.z + Li1.w * Lj1.w;
                        G[i * GS + j] = s;
                    }
                }
            }
            __syncthreads();
        }

        // Phase D: invert 8x8 diagonal blocks
        if (t < 64) {
            const int bi = t >> 3, c = t & 7;
            const int base = bi * 8;
            float m[8];
            #pragma unroll
            for (int r = 0; r < 8; ++r) {
                float s = (r == c) ? 1.0f : 0.0f;
                #pragma unroll
                for (int k = 0; k < r; ++k)
                    s -= G[(base + r) * GS + base + k] * m[k];
                m[r] = s * G[64 * GS + base + r];
            }
            #pragma unroll
            for (int r = 0; r < 8; ++r) Lti[(base + r) * 8 + c] = m[r];
        }
        __syncthreads();

        // Phase E: block forward substitution, thread = column
        if (t < 128) {
            const int c = t;
            for (int i = 0; i < 8; ++i) {
                float Tv[8];
                #pragma unroll
                for (int r = 0; r < 8; ++r) Tv[r] = Y[(i * 8 + r) * YS + c];
                for (int k = 0; k < i; ++k) {
                    #pragma unroll
                    for (int kk = 0; kk < 8; ++kk) {
                        const float z = Y[(k * 8 + kk) * YS + c];
                        #pragma unroll
                        for (int r = 0; r < 8; ++r)
                            Tv[r] -= G[(i * 8 + r) * GS + k * 8 + kk] * z;
                    }
                }
                #pragma unroll
                for (int r = 0; r < 8; ++r) {
                    float z = 0.0f;
                    #pragma unroll
                    for (int rp = 0; rp <= r; ++rp)
                        z += Lti[(i * 8 + r) * 8 + rp] * Tv[rp];
                    Y[(i * 8 + r) * YS + c] = z;
                }
            }
        }
        __syncthreads();

        // Phase F: outputs
        if (t < 256) {
            for (int e = t; e < 8192; e += 256) {
                const int j = e >> 7, i = e & 127;
                Bht[((size_t)n * 64 + j) * 128 + i] = bf16_bits(Y[j * YS + i]);
            }
            for (int e = t; e < 8192; e += 256) {
                const int i = e >> 6, j = e & 63;
                Qg[(size_t)n * 8192 + e] = Y[j * YS + i];
            }
        }
    } else if (b < 192) {
        // ---------------- convert path (512-thr mapping) ----------------
        const int gid = (b - 64) * 512 + t;   // 0..65535 quarter-rows
        if (gid == 0) out[0] = 0.0f;
        const size_t base = (size_t)gid * 32;
        float s = 0.0f;
        #pragma unroll
        for (int c = 0; c < 8; ++c) {
            const f32x4 v = ((const f32x4*)(x + base))[c];
            s += v.x * v.x + v.y * v.y + v.z * v.z + v.w * v.w;
            ushort4 h;
            h.x = bf16_bits(v.x); h.y = bf16_bits(v.y);
            h.z = bf16_bits(v.z); h.w = bf16_bits(v.w);
            ((ushort4*)(xh + base))[c] = h;
        }
        s += __shfl_xor(s, 1, 64);
        s += __shfl_xor(s, 2, 64);
        if ((gid & 3) == 0) nrm[gid >> 2] = s;
    }

    cg::this_grid().sync();   // Bht/Qg/xh/nrm globally visible

    // ======================= stage 2: gemm + argmax (R18 body) =============
    unsigned short* ldsA = (unsigned short*)smem;        // 16384 B
    float* scL = (float*)(smem + 16384);                 // 64*65*4 = 16640 B
    float* mrg = (float*)(smem + 33024);                 // [8][64][3] = 6144 B
    const int w = t >> 6, lane = t & 63;
    const int m0 = b * 64;
    const int lm = lane & 15, lg = lane >> 4;
    if (t == 0) scnt = 0;
    if (t < 8) scorr[t] = 0.0f;

    // ---- stage xh tile (swizzled, linear LDS dest; 8 waves x 2 ops) ----
    {
        const int rl = lane >> 4, sp = lane & 15;
        #pragma unroll
        for (int q = 0; q < 2; ++q) {
            const int row = w * 8 + q * 4 + rl;
            const int c = sp ^ (row & 15);
            gl_lds16(xh + (size_t)(m0 + row) * 128 + c * 8,
                     &ldsA[(w * 8 + q * 4) * 128]);
        }
    }
    __syncthreads();

    // ---- sample frags register-resident: 4 st x 4 ks (64 VGPR) ----
    s16x8 bfr[4][4];
    #pragma unroll
    for (int st = 0; st < 4; ++st) {
        const int r = st * 16 + lm;
        #pragma unroll
        for (int ks = 0; ks < 4; ++ks) {
            const int p = (ks * 4 + lg) ^ (r & 15);
            bfr[st][ks] = *(const s16x8*)&ldsA[r * 128 + p * 8];
        }
    }

    float v1[4] = {-1e30f, -1e30f, -1e30f, -1e30f};
    float v2[4] = {-1e30f, -1e30f, -1e30f, -1e30f};
    int   n1[4] = {0, 0, 0, 0};

    const unsigned short* afbase = Bht + (size_t)lm * 128 + lg * 8;

#define LOAD_AF(dst, cc) do {                                                   \
    const unsigned short* bp = afbase + (size_t)(cc) * 8192;                    \
    _Pragma("unroll")                                                           \
    for (int mt_ = 0; mt_ < 4; ++mt_)                                           \
        _Pragma("unroll")                                                       \
        for (int ks_ = 0; ks_ < 4; ++ks_)                                       \
            dst[mt_][ks_] = *(const s16x8*)(bp + mt_ * 2048 + ks_ * 32);        \
} while (0)

#define PROC(af, cc) do {                                                       \
    _Pragma("unroll")                                                           \
    for (int st_ = 0; st_ < 4; ++st_) {                                         \
        f32x4 ac0 = {0.f,0.f,0.f,0.f}, ac1 = {0.f,0.f,0.f,0.f};                 \
        f32x4 ac2 = {0.f,0.f,0.f,0.f}, ac3 = {0.f,0.f,0.f,0.f};                 \
        __builtin_amdgcn_s_setprio(1);                                          \
        _Pragma("unroll")                                                       \
        for (int ks_ = 0; ks_ < 4; ++ks_) {                                     \
            ac0 = __builtin_amdgcn_mfma_f32_16x16x32_bf16(af[0][ks_], bfr[st_][ks_], ac0, 0, 0, 0); \
            ac1 = __builtin_amdgcn_mfma_f32_16x16x32_bf16(af[1][ks_], bfr[st_][ks_], ac1, 0, 0, 0); \
            ac2 = __builtin_amdgcn_mfma_f32_16x16x32_bf16(af[2][ks_], bfr[st_][ks_], ac2, 0, 0, 0); \
            ac3 = __builtin_amdgcn_mfma_f32_16x16x32_bf16(af[3][ks_], bfr[st_][ks_], ac3, 0, 0, 0); \
        }                                                                       \
        __builtin_amdgcn_s_setprio(0);                                          \
        float q0 = ac0[0]*ac0[0]; q0 = fmaf(ac0[1],ac0[1],q0);                  \
        q0 = fmaf(ac0[2],ac0[2],q0); q0 = fmaf(ac0[3],ac0[3],q0);               \
        float q1 = ac1[0]*ac1[0]; q1 = fmaf(ac1[1],ac1[1],q1);                  \
        q1 = fmaf(ac1[2],ac1[2],q1); q1 = fmaf(ac1[3],ac1[3],q1);               \
        float q2 = ac2[0]*ac2[0]; q2 = fmaf(ac2[1],ac2[1],q2);                  \
        q2 = fmaf(ac2[2],ac2[2],q2); q2 = fmaf(ac2[3],ac2[3],q2);               \
        float q3 = ac3[0]*ac3[0]; q3 = fmaf(ac3[1],ac3[1],q3);                  \
        q3 = fmaf(ac3[2],ac3[2],q3); q3 = fmaf(ac3[3],ac3[3],q3);               \
        float s_ = ((q0 + q1) + q2) + q3;                                       \
        s_ += __shfl_xor(s_, 16, 64);                                           \
        s_ += __shfl_xor(s_, 32, 64);                                           \
        if (lg == 0) scL[(st_ * 16 + lm) * 65 + (cc)] = s_;                     \
        if (s_ > v1[st_]) { v2[st_] = v1[st_]; v1[st_] = s_; n1[st_] = (cc); }  \
        else v2[st_] = fmaxf(v2[st_], s_);                                      \
    }                                                                           \
} while (0)

    {
        const int cb = w * 8;
        s16x8 afA[4][4], afB[4][4];
        LOAD_AF(afA, cb);
        #pragma unroll 1
        for (int ci = 0; ci < 8; ci += 2) {
            LOAD_AF(afB, cb + ci + 1);
            PROC(afA, cb + ci);
            if (ci < 6) LOAD_AF(afA, cb + ci + 2);
            PROC(afB, cb + ci + 1);
        }
    }
#undef LOAD_AF
#undef PROC

    // publish per-wave top-2 (one lane per sample)
    if (lg == 0) {
        #pragma unroll
        for (int st = 0; st < 4; ++st) {
            mrg[(w * 64 + st * 16 + lm) * 3 + 0] = v1[st];
            mrg[(w * 64 + st * 16 + lm) * 3 + 1] = v2[st];
            mrg[(w * 64 + st * 16 + lm) * 3 + 2] = (float)n1[st];
        }
    }
    __syncthreads();

    // wave 0: 8-way merge, labels, flags, loss partial
    if (t < 64) {
        float b1 = -1e30f, b2 = -1e30f;
        int bn = 0;
        #pragma unroll
        for (int ww = 0; ww < 8; ++ww) {
            const float a1 = mrg[(ww * 64 + t) * 3 + 0];
            const float a2 = mrg[(ww * 64 + t) * 3 + 1];
            const int an = (int)mrg[(ww * 64 + t) * 3 + 2];
            if (a1 > b1) { b2 = fmaxf(b1, a2); b1 = a1; bn = an; }
            else b2 = fmaxf(b2, a1);
        }
        out[1 + m0 + t] = (float)bn;
        if (b1 - b2 < TAU) { const int i = atomicAdd(&scnt, 1); sflags[i] = t; }
        float err = nrm[m0 + t] - b1;
        err += __shfl_xor(err, 1, 64);
        err += __shfl_xor(err, 2, 64);
        err += __shfl_xor(err, 4, 64);
        err += __shfl_xor(err, 8, 64);
        err += __shfl_xor(err, 16, 64);
        err += __shfl_xor(err, 32, 64);
        if (t == 0) ssum = err;
    }
    __syncthreads();

    // cooperative exact rescore of flagged samples (S row from scL)
    const int nf = scnt;
    float corr = 0.0f;
    for (int f = w; f < nf; f += 8) {
        const int s = sflags[f];
        const int b2 = m0 + s;
        const float v = scL[s * 65 + lane];
        float vm = v;
        for (int off = 32; off; off >>= 1) vm = fmaxf(vm, __shfl_xor(vm, off, 64));
        unsigned long long mask = __ballot((vm - v) < TAU);
        float best = -1e30f;
        int bn = 0;
        while (mask) {
            const int nn = (int)__builtin_ctzll(mask);
            mask &= mask - 1;
            const float* Qn = Qg + (size_t)nn * 8192;
            const float* xb = x + (size_t)b2 * 128;
            float d0 = 0.0f, d1 = 0.0f, d2 = 0.0f, d3 = 0.0f;
            #pragma unroll
            for (int i = 0; i < 128; i += 4) {
                d0 = fmaf(Qn[(i + 0) * 64 + lane], xb[i + 0], d0);
                d1 = fmaf(Qn[(i + 1) * 64 + lane], xb[i + 1], d1);
                d2 = fmaf(Qn[(i + 2) * 64 + lane], xb[i + 2], d2);
                d3 = fmaf(Qn[(i + 3) * 64 + lane], xb[i + 3], d3);
            }
            const float dot = (d0 + d1) + (d2 + d3);
            float sv = dot * dot;
            for (int off = 32; off; off >>= 1) sv += __shfl_xor(sv, off, 64);
            if (sv > best) { best = sv; bn = nn; }
        }
        if (lane == 0) {
            out[1 + b2] = (float)bn;
            corr += vm - best;   // replace approx top score with exact best
        }
    }
    if (lane == 0 && corr != 0.0f) scorr[w] += corr;
    __syncthreads();
    if (t == 0)
        atomicAdd(out, ssum + scorr[0] + scorr[1] + scorr[2] + scorr[3]
                       + scorr[4] + scorr[5] + scorr[6] + scorr[7]);
}

// ---------------------------------------------------------------------------
extern "C" void kernel_launch(void* const* d_in, const int* in_sizes, int n_in,
                              void* d_out, int out_size, void* d_ws, size_t ws_size,
                              hipStream_t stream) {
    const float* x = (const float*)d_in[0];   // [16384, 128]
    const float* D = (const float*)d_in[1];   // [64, 128, 64]
    float* out = (float*)d_out;               // [1 + 16384]

    char* ws = (char*)d_ws;
    unsigned short* xh  = (unsigned short*)(ws);                 // 4 MB
    unsigned short* Bht = (unsigned short*)(ws + (4u << 20));    // 1 MB
    float* Qg           = (float*)(ws + (5u << 20));             // 2 MB
    float* nrm          = (float*)(ws + (11u << 20));            // 64 KB

    void* args[] = {(void*)&x, (void*)&D, (void*)&xh, (void*)&nrm,
                    (void*)&Qg, (void*)&Bht, (void*)&out};
    hipLaunchCooperativeKernel((const void*)fused_kfactor,
                               dim3(256), dim3(512), args, 0, stream);
}

// Round 11
// 141.298 us; speedup vs baseline: 1.3260x; 1.3260x over previous
//
#include <hip/hip_runtime.h>
#include <hip/hip_bf16.h>

#define B_N 16384
#define TAU 0.25f
#define GS 68     // G leading dim (floats); 16B-aligned rows
#define YS 133    // Y leading dim (floats); ODD -> scalar access conflict-free

typedef float f32x4 __attribute__((ext_vector_type(4)));
typedef short s16x8 __attribute__((ext_vector_type(8)));

__device__ __forceinline__ void gl_lds16(const void* g, void* l) {
    __builtin_amdgcn_global_load_lds(
        (const __attribute__((address_space(1))) void*)g,
        (__attribute__((address_space(3))) void*)l, 16, 0, 0);
}

__device__ __forceinline__ unsigned short bf16_bits(float v) {
    __hip_bfloat16 h = __float2bfloat16(v);
    return *reinterpret_cast<unsigned short*>(&h);
}

__device__ __forceinline__ float readlane_f(float v, int l) {
    return __int_as_float(__builtin_amdgcn_readlane(__float_as_int(v), l));
}

// ---------------------------------------------------------------------------
// Kernel 1 (merged): blocks 0..63 = per-cluster prep; blocks 64..319 = convert.
// R17 internals (R0 base + readlane Cholesky diag chain) + vectorized Phase F
// stores (ushort4 Bht / f32x4 Qg; identical values & addresses).
// ---------------------------------------------------------------------------
__global__ __launch_bounds__(256) void prep_convert(const float* __restrict__ x,
                                                    const float* __restrict__ D,
                                                    unsigned short* __restrict__ xh,
                                                    float* __restrict__ nrm,
                                                    float* __restrict__ Qg,
                                                    unsigned short* __restrict__ Bht,
                                                    float* __restrict__ out) {
    const int t = threadIdx.x;

    if (blockIdx.x >= 64) {
        // ---------------- convert path ----------------
        const int gid = (blockIdx.x - 64) * 256 + t;   // 0..65535 quarter-rows
        if (gid == 0) out[0] = 0.0f;
        const size_t base = (size_t)gid * 32;
        float s = 0.0f;
        #pragma unroll
        for (int c = 0; c < 8; ++c) {
            const f32x4 v = ((const f32x4*)(x + base))[c];
            s += v.x * v.x + v.y * v.y + v.z * v.z + v.w * v.w;
            ushort4 h;
            h.x = bf16_bits(v.x); h.y = bf16_bits(v.y);
            h.z = bf16_bits(v.z); h.w = bf16_bits(v.w);
            ((ushort4*)(xh + base))[c] = h;
        }
        s += __shfl_xor(s, 1, 64);
        s += __shfl_xor(s, 2, 64);
        if ((gid & 3) == 0) nrm[gid >> 2] = s;
        return;
    }

    // ---------------- prep path ----------------
    __shared__ float Y[64 * YS];                      // D^T -> Q^T (in place)
    __shared__ __align__(16) float G[64 * GS + 64];   // gram -> L; tail = 1/L[i][i]
    __shared__ __align__(16) float Lti[8 * 8 * 8];    // 8x8 diag-block inverses
    const int n = blockIdx.x;
    const float* Dn = D + (size_t)n * 8192;

    // Phase A: Y[j][c] = Dn[c][j]
    for (int e4 = t; e4 < 2048; e4 += 256) {
        const int c = e4 >> 4, j4 = (e4 & 15) * 4;
        const f32x4 v = ((const f32x4*)Dn)[e4];
        Y[(j4 + 0) * YS + c] = v.x;
        Y[(j4 + 1) * YS + c] = v.y;
        Y[(j4 + 2) * YS + c] = v.z;
        Y[(j4 + 3) * YS + c] = v.w;
    }

    // Phase B: gram from global (L1-hot)
    {
        const int a0 = (t & 15) * 4, b0 = (t >> 4) * 4;
        float acc[4][4] = {};
        #pragma unroll 4
        for (int i = 0; i < 128; ++i) {
            const f32x4 av = *(const f32x4*)(Dn + i * 64 + a0);
            const f32x4 bv = *(const f32x4*)(Dn + i * 64 + b0);
            const float aa[4] = {av.x, av.y, av.z, av.w};
            const float bb[4] = {bv.x, bv.y, bv.z, bv.w};
            #pragma unroll
            for (int p = 0; p < 4; ++p)
                #pragma unroll
                for (int q = 0; q < 4; ++q) acc[p][q] = fmaf(aa[p], bb[q], acc[p][q]);
        }
        #pragma unroll
        for (int p = 0; p < 4; ++p)
            #pragma unroll
            for (int q = 0; q < 4; ++q) G[(a0 + p) * GS + b0 + q] = acc[p][q];
    }
    __syncthreads();

    // Phase C: blocked Cholesky, register-resident 8x8 panels (readlane chain)
    #pragma unroll
    for (int p8 = 0; p8 < 8; ++p8) {
        const int pb = p8 * 8;
        if (t < 64) {
            const int lane = t;
            const f32x4 v0 = *(const f32x4*)&G[lane * GS + pb];
            const f32x4 v1 = *(const f32x4*)&G[lane * GS + pb + 4];
            float g[8] = {v0.x, v0.y, v0.z, v0.w, v1.x, v1.y, v1.z, v1.w};
            #pragma unroll
            for (int kk = 0; kk < 8; ++kk) {
                const int k = pb + kk;
                const float dk = readlane_f(g[kk], k);
                const float rinv = 1.0f / sqrtf(dk);
                const float lik = g[kk] * rinv;
                g[kk] = lik;
                if (lane == 0) G[64 * GS + k] = rinv;
                #pragma unroll
                for (int jj = kk + 1; jj < 8; ++jj) {
                    const float ljk = readlane_f(lik, pb + jj);
                    g[jj] -= lik * ljk;
                }
            }
            *(f32x4*)&G[lane * GS + pb]     = (f32x4){g[0], g[1], g[2], g[3]};
            *(f32x4*)&G[lane * GS + pb + 4] = (f32x4){g[4], g[5], g[6], g[7]};
        }
        __syncthreads();
        const int base = pb + 8;
        if (base < 64) {
            for (int i = base + (t >> 5); i < 64; i += 8) {
                const f32x4 Li0 = *(const f32x4*)&G[i * GS + pb];
                const f32x4 Li1 = *(const f32x4*)&G[i * GS + pb + 4];
                for (int j = base + (t & 31); j < 64; j += 32) {
                    const f32x4 Lj0 = *(const f32x4*)&G[j * GS + pb];
                    const f32x4 Lj1 = *(const f32x4*)&G[j * GS + pb + 4];
                    float s = G[i * GS + j];
                    s -= Li0.x * Lj0.x + Li0.y * Lj0.y + Li0.z * Lj0.z + Li0.w * Lj0.w;
                    s -= Li1.x * Lj1.x + Li1.y * Lj1.y + Li1.z * Lj1.z + Li1.w * Lj1.w;
                    G[i * GS + j] = s;
                }
            }
        }
        __syncthreads();
    }

    // Phase D: invert 8x8 diagonal blocks
    if (t < 64) {
        const int bi = t >> 3, c = t & 7;
        const int base = bi * 8;
        float m[8];
        #pragma unroll
        for (int r = 0; r < 8; ++r) {
            float s = (r == c) ? 1.0f : 0.0f;
            #pragma unroll
            for (int k = 0; k < r; ++k)
                s -= G[(base + r) * GS + base + k] * m[k];
            m[r] = s * G[64 * GS + base + r];
        }
        #pragma unroll
        for (int r = 0; r < 8; ++r) Lti[(base + r) * 8 + c] = m[r];
    }
    __syncthreads();

    // Phase E: block forward substitution, thread = column
    if (t < 128) {
        const int c = t;
        for (int i = 0; i < 8; ++i) {
            float Tv[8];
            #pragma unroll
            for (int r = 0; r < 8; ++r) Tv[r] = Y[(i * 8 + r) * YS + c];
            for (int k = 0; k < i; ++k) {
                #pragma unroll
                for (int kk = 0; kk < 8; ++kk) {
                    const float z = Y[(k * 8 + kk) * YS + c];
                    #pragma unroll
                    for (int r = 0; r < 8; ++r)
                        Tv[r] -= G[(i * 8 + r) * GS + k * 8 + kk] * z;
                }
            }
            #pragma unroll
            for (int r = 0; r < 8; ++r) {
                float z = 0.0f;
                #pragma unroll
                for (int rp = 0; rp <= r; ++rp)
                    z += Lti[(i * 8 + r) * 8 + rp] * Tv[rp];
                Y[(i * 8 + r) * YS + c] = z;
            }
        }
    }
    __syncthreads();

    // Phase F: outputs, vectorized stores (identical values/addresses).
    // Pass 1: Bht[n][j][i4..i4+3] as ushort4 (2048 quads).
    for (int e4 = t; e4 < 2048; e4 += 256) {
        const int j = e4 >> 5, i4 = (e4 & 31) * 4;
        ushort4 h;
        h.x = bf16_bits(Y[j * YS + i4 + 0]);
        h.y = bf16_bits(Y[j * YS + i4 + 1]);
        h.z = bf16_bits(Y[j * YS + i4 + 2]);
        h.w = bf16_bits(Y[j * YS + i4 + 3]);
        *(ushort4*)&Bht[((size_t)n * 64 + j) * 128 + i4] = h;
    }
    // Pass 2: Qg[n][i][j4..j4+3] as f32x4 (2048 quads).
    for (int e4 = t; e4 < 2048; e4 += 256) {
        const int i = e4 >> 4, j4 = (e4 & 15) * 4;
        const f32x4 v = {Y[(j4 + 0) * YS + i], Y[(j4 + 1) * YS + i],
                         Y[(j4 + 2) * YS + i], Y[(j4 + 3) * YS + i]};
        *(f32x4*)&Qg[(size_t)n * 8192 + i * 64 + j4] = v;
    }
}

// ---------------------------------------------------------------------------
// Kernel 2 (R18, byte-identical — best measured: 47.7 us): barrier-free fused
// scores + argmax. 256 blocks x 64 samples x 512 threads; each wave owns 8
// whole clusters; af gathered global->VGPR (L2-resident, each 64B line touched
// once per wave); per-lane top-2; 8-way merge; exact rescore protects labels.
// ---------------------------------------------------------------------------
__global__ __launch_bounds__(512) void gemm_argmax(const unsigned short* __restrict__ xh,
                                                   const unsigned short* __restrict__ Bht,
                                                   const float* __restrict__ nrm,
                                                   const float* __restrict__ x,
                                                   const float* __restrict__ Qg,
                                                   float* __restrict__ out) {
    __shared__ __align__(16) unsigned short ldsA[64 * 128];  // 16 KB xh tile
    __shared__ float scL[64 * 65];                           // 16.64 KB scores
    __shared__ float mrg[8][64][3];                          // 6 KB top-2 merge
    __shared__ int sflags[64];
    __shared__ int scnt;
    __shared__ float ssum;
    __shared__ float scorr[8];

    const int t = threadIdx.x, w = t >> 6, lane = t & 63;
    const int m0 = blockIdx.x * 64;
    const int lm = lane & 15, lg = lane >> 4;
    if (t == 0) scnt = 0;
    if (t < 8) scorr[t] = 0.0f;

    // ---- stage xh tile (swizzled, linear LDS dest; 8 waves x 2 ops) ----
    {
        const int rl = lane >> 4, sp = lane & 15;
        #pragma unroll
        for (int q = 0; q < 2; ++q) {
            const int row = w * 8 + q * 4 + rl;
            const int c = sp ^ (row & 15);
            gl_lds16(xh + (size_t)(m0 + row) * 128 + c * 8,
                     &ldsA[(w * 8 + q * 4) * 128]);
        }
    }
    __syncthreads();

    // ---- sample frags register-resident: 4 st x 4 ks (64 VGPR) ----
    s16x8 bfr[4][4];
    #pragma unroll
    for (int st = 0; st < 4; ++st) {
        const int r = st * 16 + lm;
        #pragma unroll
        for (int ks = 0; ks < 4; ++ks) {
            const int p = (ks * 4 + lg) ^ (r & 15);
            bfr[st][ks] = *(const s16x8*)&ldsA[r * 128 + p * 8];
        }
    }

    float v1[4] = {-1e30f, -1e30f, -1e30f, -1e30f};
    float v2[4] = {-1e30f, -1e30f, -1e30f, -1e30f};
    int   n1[4] = {0, 0, 0, 0};

    // per-lane global base for af reads (16B aligned)
    const unsigned short* afbase = Bht + (size_t)lm * 128 + lg * 8;

#define LOAD_AF(dst, cc) do {                                                   \
    const unsigned short* bp = afbase + (size_t)(cc) * 8192;                    \
    _Pragma("unroll")                                                           \
    for (int mt_ = 0; mt_ < 4; ++mt_)                                           \
        _Pragma("unroll")                                                       \
        for (int ks_ = 0; ks_ < 4; ++ks_)                                       \
            dst[mt_][ks_] = *(const s16x8*)(bp + mt_ * 2048 + ks_ * 32);        \
} while (0)

#define PROC(af, cc) do {                                                       \
    _Pragma("unroll")                                                           \
    for (int st_ = 0; st_ < 4; ++st_) {                                         \
        f32x4 ac0 = {0.f,0.f,0.f,0.f}, ac1 = {0.f,0.f,0.f,0.f};                 \
        f32x4 ac2 = {0.f,0.f,0.f,0.f}, ac3 = {0.f,0.f,0.f,0.f};                 \
        __builtin_amdgcn_s_setprio(1);                                          \
        _Pragma("unroll")                                                       \
        for (int ks_ = 0; ks_ < 4; ++ks_) {                                     \
            ac0 = __builtin_amdgcn_mfma_f32_16x16x32_bf16(af[0][ks_], bfr[st_][ks_], ac0, 0, 0, 0); \
            ac1 = __builtin_amdgcn_mfma_f32_16x16x32_bf16(af[1][ks_], bfr[st_][ks_], ac1, 0, 0, 0); \
            ac2 = __builtin_amdgcn_mfma_f32_16x16x32_bf16(af[2][ks_], bfr[st_][ks_], ac2, 0, 0, 0); \
            ac3 = __builtin_amdgcn_mfma_f32_16x16x32_bf16(af[3][ks_], bfr[st_][ks_], ac3, 0, 0, 0); \
        }                                                                       \
        __builtin_amdgcn_s_setprio(0);                                          \
        float q0 = ac0[0]*ac0[0]; q0 = fmaf(ac0[1],ac0[1],q0);                  \
        q0 = fmaf(ac0[2],ac0[2],q0); q0 = fmaf(ac0[3],ac0[3],q0);               \
        float q1 = ac1[0]*ac1[0]; q1 = fmaf(ac1[1],ac1[1],q1);                  \
        q1 = fmaf(ac1[2],ac1[2],q1); q1 = fmaf(ac1[3],ac1[3],q1);               \
        float q2 = ac2[0]*ac2[0]; q2 = fmaf(ac2[1],ac2[1],q2);                  \
        q2 = fmaf(ac2[2],ac2[2],q2); q2 = fmaf(ac2[3],ac2[3],q2);               \
        float q3 = ac3[0]*ac3[0]; q3 = fmaf(ac3[1],ac3[1],q3);                  \
        q3 = fmaf(ac3[2],ac3[2],q3); q3 = fmaf(ac3[3],ac3[3],q3);               \
        float s_ = ((q0 + q1) + q2) + q3;                                       \
        s_ += __shfl_xor(s_, 16, 64);                                           \
        s_ += __shfl_xor(s_, 32, 64);                                           \
        if (lg == 0) scL[(st_ * 16 + lm) * 65 + (cc)] = s_;                     \
        if (s_ > v1[st_]) { v2[st_] = v1[st_]; v1[st_] = s_; n1[st_] = (cc); }  \
        else v2[st_] = fmaxf(v2[st_], s_);                                      \
    }                                                                           \
} while (0)

    {
        const int cb = w * 8;
        s16x8 afA[4][4], afB[4][4];
        LOAD_AF(afA, cb);
        #pragma unroll 1
        for (int ci = 0; ci < 8; ci += 2) {
            LOAD_AF(afB, cb + ci + 1);
            PROC(afA, cb + ci);
            if (ci < 6) LOAD_AF(afA, cb + ci + 2);
            PROC(afB, cb + ci + 1);
        }
    }
#undef LOAD_AF
#undef PROC

    // publish per-wave top-2 (one lane per sample)
    if (lg == 0) {
        #pragma unroll
        for (int st = 0; st < 4; ++st) {
            mrg[w][st * 16 + lm][0] = v1[st];
            mrg[w][st * 16 + lm][1] = v2[st];
            mrg[w][st * 16 + lm][2] = (float)n1[st];
        }
    }
    __syncthreads();

    // wave 0: 8-way merge, labels, flags, loss partial
    if (t < 64) {
        float b1 = -1e30f, b2 = -1e30f;
        int bn = 0;
        #pragma unroll
        for (int ww = 0; ww < 8; ++ww) {
            const float a1 = mrg[ww][t][0];
            const float a2 = mrg[ww][t][1];
            const int an = (int)mrg[ww][t][2];
            if (a1 > b1) { b2 = fmaxf(b1, a2); b1 = a1; bn = an; }
            else b2 = fmaxf(b2, a1);
        }
        out[1 + m0 + t] = (float)bn;
        if (b1 - b2 < TAU) { const int i = atomicAdd(&scnt, 1); sflags[i] = t; }
        float err = nrm[m0 + t] - b1;
        err += __shfl_xor(err, 1, 64);
        err += __shfl_xor(err, 2, 64);
        err += __shfl_xor(err, 4, 64);
        err += __shfl_xor(err, 8, 64);
        err += __shfl_xor(err, 16, 64);
        err += __shfl_xor(err, 32, 64);
        if (t == 0) ssum = err;
    }
    __syncthreads();

    // cooperative exact rescore of flagged samples (S row from scL)
    const int nf = scnt;
    float corr = 0.0f;
    for (int f = w; f < nf; f += 8) {
        const int s = sflags[f];
        const int b2 = m0 + s;
        const float v = scL[s * 65 + lane];
        float vm = v;
        for (int off = 32; off; off >>= 1) vm = fmaxf(vm, __shfl_xor(vm, off, 64));
        unsigned long long mask = __ballot((vm - v) < TAU);
        float best = -1e30f;
        int bn = 0;
        while (mask) {
            const int nn = (int)__builtin_ctzll(mask);
            mask &= mask - 1;
            const float* Qn = Qg + (size_t)nn * 8192;
            const float* xb = x + (size_t)b2 * 128;
            float d0 = 0.0f, d1 = 0.0f, d2 = 0.0f, d3 = 0.0f;
            #pragma unroll
            for (int i = 0; i < 128; i += 4) {
                d0 = fmaf(Qn[(i + 0) * 64 + lane], xb[i + 0], d0);
                d1 = fmaf(Qn[(i + 1) * 64 + lane], xb[i + 1], d1);
                d2 = fmaf(Qn[(i + 2) * 64 + lane], xb[i + 2], d2);
                d3 = fmaf(Qn[(i + 3) * 64 + lane], xb[i + 3], d3);
            }
            const float dot = (d0 + d1) + (d2 + d3);
            float sv = dot * dot;
            for (int off = 32; off; off >>= 1) sv += __shfl_xor(sv, off, 64);
            if (sv > best) { best = sv; bn = nn; }
        }
        if (lane == 0) {
            out[1 + b2] = (float)bn;
            corr += vm - best;   // replace approx top score with exact best
        }
    }
    if (lane == 0 && corr != 0.0f) scorr[w] += corr;
    __syncthreads();
    if (t == 0)
        atomicAdd(out, ssum + scorr[0] + scorr[1] + scorr[2] + scorr[3]
                       + scorr[4] + scorr[5] + scorr[6] + scorr[7]);
}

// ---------------------------------------------------------------------------
extern "C" void kernel_launch(void* const* d_in, const int* in_sizes, int n_in,
                              void* d_out, int out_size, void* d_ws, size_t ws_size,
                              hipStream_t stream) {
    const float* x = (const float*)d_in[0];   // [16384, 128]
    const float* D = (const float*)d_in[1];   // [64, 128, 64]
    float* out = (float*)d_out;               // [1 + 16384]

    char* ws = (char*)d_ws;
    unsigned short* xh  = (unsigned short*)(ws);                 // 4 MB
    unsigned short* Bht = (unsigned short*)(ws + (4u << 20));    // 1 MB
    float* Qg           = (float*)(ws + (5u << 20));             // 2 MB
    float* nrm          = (float*)(ws + (11u << 20));            // 64 KB

    prep_convert<<<320, 256, 0, stream>>>(x, D, xh, nrm, Qg, Bht, out);
    gemm_argmax<<<256, 512, 0, stream>>>(xh, Bht, nrm, x, Qg, out);
}